// Round 11
// baseline (738.720 us; speedup 1.0000x reference)
//
#include <hip/hip_runtime.h>
#include <math.h>

#define G_ 320
#define N_ 1000
#define T_ 10
#define C_ 96
#define E_ 8000
#define QN 250          // nodes per quarter (4 quarters)
#define CAP 2816        // slot capacity per quarter (mean ~2250, >14 sigma)
#define EPT 5           // slots per thread in main logit pass
#define REP_LOGIT 16
#define REP_SM 64
#define REP_WR 8

// ws layout (bytes):
//       0: P      96 float4      (wl, wr, bl+br, 0.4*att)
//    1536: lin3   3 f
//    1552: offsG  4*251 i
//    5568: slots  4*CAP int2
// 1000000: scr   (diagnostic dumps)

// ---------------- kA: shared CSR build, one block per quarter ----------------
__global__ __launch_bounds__(512) void kA(
        const int* __restrict__ ei,
        const float* __restrict__ Wl, const float* __restrict__ bl,
        const float* __restrict__ Wr, const float* __restrict__ br,
        const float* __restrict__ att,
        float4* __restrict__ P, float* __restrict__ lin3g,
        int* __restrict__ offsG, int2* __restrict__ slots) {
    __shared__ int cnt[256], cur[256], offsL[260];
    const int tid = threadIdx.x;
    const int q = blockIdx.x;
    const int lo = q * QN;

    if (q == 0) {
        if (tid < C_)
            P[tid] = make_float4(Wl[tid], Wr[tid], bl[tid] + br[tid], 0.4f * att[tid]);
        int w = tid >> 6, lane = tid & 63;
        if (w < 3) {
            float s = 0.f;
            for (int i = lane; i < C_; i += 64) {
                float a = att[i];
                float m = (w == 0) ? Wl[i] : (w == 1) ? Wr[i] : (bl[i] + br[i]);
                s += a * m;
            }
            for (int off = 32; off; off >>= 1) s += __shfl_down(s, off);
            if (lane == 0) lin3g[w] = 0.6f * s;
        }
    }
    for (int i = tid; i < 256; i += 512) cnt[i] = (i < QN) ? 1 : 0;
    __syncthreads();

    const int4* d4 = (const int4*)(ei + E_);
    const int4* s4 = (const int4*)ei;
    for (int j = tid; j < E_ / 4; j += 512) {
        int4 d = d4[j];
        int r0 = d.x - lo, r1 = d.y - lo, r2 = d.z - lo, r3 = d.w - lo;
        if ((unsigned)r0 < (unsigned)QN) atomicAdd(&cnt[r0], 1);
        if ((unsigned)r1 < (unsigned)QN) atomicAdd(&cnt[r1], 1);
        if ((unsigned)r2 < (unsigned)QN) atomicAdd(&cnt[r2], 1);
        if ((unsigned)r3 < (unsigned)QN) atomicAdd(&cnt[r3], 1);
    }
    __syncthreads();

    if (tid < 64) {
        int b4 = tid * 4;
        int a0 = cnt[b4], a1 = cnt[b4 + 1], a2 = cnt[b4 + 2], a3 = cnt[b4 + 3];
        int s1 = a0 + a1, s2 = s1 + a2, s3 = s2 + a3;
        int pre = s3;
        for (int off = 1; off < 64; off <<= 1) {
            int tv = __shfl_up(pre, off);
            if (tid >= off) pre += tv;
        }
        int base = pre - s3;
        offsL[b4] = base;          cur[b4] = base;
        offsL[b4 + 1] = base + a0; cur[b4 + 1] = base + a0;
        offsL[b4 + 2] = base + s1; cur[b4 + 2] = base + s1;
        offsL[b4 + 3] = base + s2; cur[b4 + 3] = base + s2;
    }
    __syncthreads();

    int2* sl = slots + (size_t)q * CAP;
    for (int j = tid; j < E_ / 4; j += 512) {
        int4 d = d4[j];
        int4 s = s4[j];
#define SCAT(DD, SS) { int r = (DD) - lo;                                    \
        if ((unsigned)r < (unsigned)QN) {                                    \
            int pos = atomicAdd(&cur[r], 1);                                 \
            sl[pos] = make_int2((SS), (DD)); } }
        SCAT(d.x, s.x) SCAT(d.y, s.y) SCAT(d.z, s.z) SCAT(d.w, s.w)
#undef SCAT
    }
    for (int i = tid; i < QN; i += 512) {
        int pos = atomicAdd(&cur[i], 1);
        sl[pos] = make_int2(lo + i, lo + i);
    }
    for (int i = tid; i <= QN; i += 512) offsG[q * (QN + 1) + i] = offsL[i];
}

// =============== DIAGNOSTIC kernels (write scratch / pre-output) ===============

// kD2: stage + REP_LOGIT x logit pass. Isolates gather+FMA-loop cost.
__global__ __launch_bounds__(512, 4) void kD2(
        const float* __restrict__ x, const float4* __restrict__ P,
        const float* __restrict__ lin3g, const int* __restrict__ offsG,
        const int2* __restrict__ slots, float* __restrict__ scr) {
    __shared__ float xgs[N_];
    __shared__ float2 LU[CAP];
    __shared__ int offsL[QN + 1];
    const int tid = threadIdx.x;
    const int q = blockIdx.x, g = blockIdx.y;
    const float* xg = x + g * N_;
    if (tid < N_ / 4) ((float4*)xgs)[tid] = ((const float4*)xg)[tid];
    for (int i = tid; i <= QN; i += 512) offsL[i] = offsG[q * (QN + 1) + i];
    __syncthreads();
    const int cntE = offsL[QN];
    const float la = lin3g[0], lb = lin3g[1], lc = lin3g[2];
    const int2* sl = slots + (size_t)q * CAP;

#pragma unroll 1
    for (int r = 0; r < REP_LOGIT; ++r) {
        float u[EPT], v[EPT], acc[EPT];
#pragma unroll
        for (int k = 0; k < EPT; k++) {
            int p = tid + k * 512;
            int2 sd = sl[p < cntE ? p : 0];
            u[k] = xgs[sd.x]; v[k] = xgs[sd.y]; acc[k] = 0.f;
        }
#pragma unroll 8
        for (int c = 0; c < C_; c++) {
            float4 qv = P[c];
#pragma unroll
            for (int k = 0; k < EPT; k++) {
                float wv = fmaf(u[k], qv.x, fmaf(v[k], qv.y, qv.z));
                acc[k] = fmaf(qv.w, fabsf(wv), acc[k]);
            }
        }
#pragma unroll
        for (int k = 0; k < EPT; k++) {
            int p = tid + k * 512;
            if (p < cntE)
                LU[p] = make_float2(fmaf(u[k], la, fmaf(v[k], lb, lc)) + acc[k], u[k]);
        }
        for (int p = tid + 512 * EPT; p < cntE; p += 512) {
            int2 sd = sl[p];
            float uu = xgs[sd.x], vv = xgs[sd.y], a2 = 0.f;
            for (int c = 0; c < C_; c++) {
                float4 qv = P[c];
                float wv = fmaf(uu, qv.x, fmaf(vv, qv.y, qv.z));
                a2 = fmaf(qv.w, fabsf(wv), a2);
            }
            LU[p] = make_float2(fmaf(uu, la, fmaf(vv, lb, lc)) + a2, uu);
        }
        asm volatile("" ::: "memory");
    }
    __syncthreads();
    scr[((q * G_ + g) * 512 + tid)] = LU[tid].x + LU[tid].y;
}

// kD3: stage + 1x logit + REP_SM x softmax. Isolates softmax cost.
__global__ __launch_bounds__(512, 4) void kD3(
        const float* __restrict__ x, const float4* __restrict__ P,
        const float* __restrict__ lin3g, const int* __restrict__ offsG,
        const int2* __restrict__ slots, float* __restrict__ scr) {
    __shared__ float xgs[N_];
    __shared__ float2 LU[CAP];
    __shared__ int offsL[QN + 1];
    __shared__ float Sloc[QN];
    const int tid = threadIdx.x;
    const int q = blockIdx.x, g = blockIdx.y;
    const float* xg = x + g * N_;
    if (tid < N_ / 4) ((float4*)xgs)[tid] = ((const float4*)xg)[tid];
    for (int i = tid; i <= QN; i += 512) offsL[i] = offsG[q * (QN + 1) + i];
    __syncthreads();
    const int cntE = offsL[QN];
    const float la = lin3g[0], lb = lin3g[1], lc = lin3g[2];
    const int2* sl = slots + (size_t)q * CAP;
    {
        float u[EPT], v[EPT], acc[EPT];
#pragma unroll
        for (int k = 0; k < EPT; k++) {
            int p = tid + k * 512;
            int2 sd = sl[p < cntE ? p : 0];
            u[k] = xgs[sd.x]; v[k] = xgs[sd.y]; acc[k] = 0.f;
        }
#pragma unroll 8
        for (int c = 0; c < C_; c++) {
            float4 qv = P[c];
#pragma unroll
            for (int k = 0; k < EPT; k++) {
                float wv = fmaf(u[k], qv.x, fmaf(v[k], qv.y, qv.z));
                acc[k] = fmaf(qv.w, fabsf(wv), acc[k]);
            }
        }
#pragma unroll
        for (int k = 0; k < EPT; k++) {
            int p = tid + k * 512;
            if (p < cntE)
                LU[p] = make_float2(fmaf(u[k], la, fmaf(v[k], lb, lc)) + acc[k], u[k]);
        }
        for (int p = tid + 512 * EPT; p < cntE; p += 512) {
            int2 sd = sl[p];
            float uu = xgs[sd.x], vv = xgs[sd.y], a2 = 0.f;
            for (int c = 0; c < C_; c++) {
                float4 qv = P[c];
                float wv = fmaf(uu, qv.x, fmaf(vv, qv.y, qv.z));
                a2 = fmaf(qv.w, fabsf(wv), a2);
            }
            LU[p] = make_float2(fmaf(uu, la, fmaf(vv, lb, lc)) + a2, uu);
        }
    }
    __syncthreads();
#pragma unroll 1
    for (int r = 0; r < REP_SM; ++r) {
        if (tid < QN) {
            int a = offsL[tid], b = offsL[tid + 1];
            float m = -INFINITY, den = 0.f, num = 0.f;
            for (int p = a; p < b; ++p) {
                float2 lu = LU[p];
                float nm = fmaxf(m, lu.x);
                float sc = __expf(m - nm);
                float ex = __expf(lu.x - nm);
                den = den * sc + ex;
                num = fmaf(ex, lu.y, num * sc);
                m = nm;
            }
            Sloc[tid] = num / den;
        }
        asm volatile("" ::: "memory");
    }
    __syncthreads();
    if (tid < QN) scr[(q * G_ + g) * QN + tid] = Sloc[tid];
}

// kD4: REP_WR x expansion write to d_out (fake S; kF overwrites later).
__global__ __launch_bounds__(512, 4) void kD4(
        const float* __restrict__ Wl, const float* __restrict__ bl,
        const float* __restrict__ bias, float4* __restrict__ out) {
    __shared__ float Sloc[QN];
    __shared__ float4 wl4[C_ / 4], cb4[C_ / 4];
    const int tid = threadIdx.x;
    const int q = blockIdx.x, g = blockIdx.y;
    const int lo = q * QN;
    const int t = g % T_;
    if (tid < C_) {
        int k2 = tid & ~1;
        float dt = __expf(-(float)k2 * (logf(10000.0f) / (float)C_));
        float ang = (float)t * dt;
        float pe = (tid & 1) ? cosf(ang) : sinf(ang);
        ((float*)wl4)[tid] = Wl[tid];
        ((float*)cb4)[tid] = bl[tid] + bias[tid] + pe;
    }
    if (tid < QN) Sloc[tid] = 1.0f + tid * 1e-3f;
    __syncthreads();
#pragma unroll 1
    for (int r = 0; r < REP_WR; ++r) {
        float4* out4 = out + (size_t)(g * N_ + lo) * (C_ / 4);
        int node = tid / 24, c4 = tid % 24;
        for (int i = tid; i < QN * (C_ / 4); i += 512) {
            float s = Sloc[node];
            float4 wv = wl4[c4], cb = cb4[c4];
            out4[i] = make_float4(fmaf(s, wv.x, cb.x), fmaf(s, wv.y, cb.y),
                                  fmaf(s, wv.z, cb.z), fmaf(s, wv.w, cb.w));
            int c4n = c4 + 8;
            int carry = (c4n >= 24) ? 1 : 0;
            node += 21 + carry;
            c4 = c4n - (carry ? 24 : 0);
        }
        asm volatile("" ::: "memory");
    }
}

// ------- kF: R8-exact fused logits + softmax + expansion (real output) -------
__global__ __launch_bounds__(512, 4) void kF(
        const float* __restrict__ x, const float4* __restrict__ P,
        const float* __restrict__ lin3g, const int* __restrict__ offsG,
        const int2* __restrict__ slots,
        const float* __restrict__ Wl, const float* __restrict__ bl,
        const float* __restrict__ bias, float4* __restrict__ out) {
    __shared__ float xgs[N_];
    __shared__ float L[CAP];
    __shared__ float U[CAP];
    __shared__ int offsL[QN + 1];
    __shared__ float Sloc[QN];
    __shared__ float4 wl4[C_ / 4], cb4[C_ / 4];
    const int tid = threadIdx.x;
    const int q = blockIdx.x;
    const int g = blockIdx.y;
    const int lo = q * QN;
    const int t = g % T_;

    const float* xg = x + g * N_;
    if (tid < N_ / 4) ((float4*)xgs)[tid] = ((const float4*)xg)[tid];
    for (int i = tid; i <= QN; i += 512) offsL[i] = offsG[q * (QN + 1) + i];
    if (tid < C_) {
        int k2 = tid & ~1;
        float dt = __expf(-(float)k2 * (logf(10000.0f) / (float)C_));
        float ang = (float)t * dt;
        float pe = (tid & 1) ? cosf(ang) : sinf(ang);
        ((float*)wl4)[tid] = Wl[tid];
        ((float*)cb4)[tid] = bl[tid] + bias[tid] + pe;
    }
    __syncthreads();
    const int cntE = offsL[QN];
    const float la = lin3g[0], lb = lin3g[1], lc = lin3g[2];
    const int2* sl = slots + (size_t)q * CAP;

    {
        float u[EPT], v[EPT], acc[EPT];
#pragma unroll
        for (int k = 0; k < EPT; k++) {
            int p = tid + k * 512;
            int2 sd = sl[p < cntE ? p : 0];
            u[k] = xgs[sd.x]; v[k] = xgs[sd.y]; acc[k] = 0.f;
        }
#pragma unroll 8
        for (int c = 0; c < C_; c++) {
            float4 qv = P[c];
#pragma unroll
            for (int k = 0; k < EPT; k++) {
                float wv = fmaf(u[k], qv.x, fmaf(v[k], qv.y, qv.z));
                acc[k] = fmaf(qv.w, fabsf(wv), acc[k]);
            }
        }
#pragma unroll
        for (int k = 0; k < EPT; k++) {
            int p = tid + k * 512;
            if (p < cntE) {
                L[p] = fmaf(u[k], la, fmaf(v[k], lb, lc)) + acc[k];
                U[p] = u[k];
            }
        }
    }
    for (int p = tid + 512 * EPT; p < cntE; p += 512) {
        int2 sd = sl[p];
        float uu = xgs[sd.x], vv = xgs[sd.y], a2 = 0.f;
        for (int c = 0; c < C_; c++) {
            float4 qv = P[c];
            float wv = fmaf(uu, qv.x, fmaf(vv, qv.y, qv.z));
            a2 = fmaf(qv.w, fabsf(wv), a2);
        }
        L[p] = fmaf(uu, la, fmaf(vv, lb, lc)) + a2;
        U[p] = uu;
    }
    __syncthreads();

    if (tid < QN) {
        int a = offsL[tid], b = offsL[tid + 1];
        float m = -INFINITY, den = 0.f, num = 0.f;
        for (int p = a; p < b; ++p) {
            float l = L[p], uu = U[p];
            float nm = fmaxf(m, l);
            float sc = __expf(m - nm);
            float ex = __expf(l - nm);
            den = den * sc + ex;
            num = fmaf(ex, uu, num * sc);
            m = nm;
        }
        Sloc[tid] = num / den;
    }
    __syncthreads();

    float4* out4 = out + (size_t)(g * N_ + lo) * (C_ / 4);
    int node = tid / 24, c4 = tid % 24;
    for (int i = tid; i < QN * (C_ / 4); i += 512) {
        float s = Sloc[node];
        float4 wv = wl4[c4], cb = cb4[c4];
        out4[i] = make_float4(fmaf(s, wv.x, cb.x), fmaf(s, wv.y, cb.y),
                              fmaf(s, wv.z, cb.z), fmaf(s, wv.w, cb.w));
        int c4n = c4 + 8;
        int carry = (c4n >= 24) ? 1 : 0;
        node += 21 + carry;
        c4 = c4n - (carry ? 24 : 0);
    }
}

extern "C" void kernel_launch(void* const* d_in, const int* in_sizes, int n_in,
                              void* d_out, int out_size, void* d_ws, size_t ws_size,
                              hipStream_t stream) {
    const float* x    = (const float*)d_in[0];
    const int*   ei   = (const int*)d_in[1];
    const float* Wl   = (const float*)d_in[2];
    const float* bl   = (const float*)d_in[3];
    const float* Wr   = (const float*)d_in[4];
    const float* br   = (const float*)d_in[5];
    const float* att  = (const float*)d_in[6];
    const float* bias = (const float*)d_in[7];
    float4* out = (float4*)d_out;

    char* ws = (char*)d_ws;
    float4* P     = (float4*)(ws + 0);
    float*  lin3g = (float*)(ws + 1536);
    int*    offsG = (int*)(ws + 1552);
    int2*   slots = (int2*)(ws + 5568);
    float*  scr   = (float*)(ws + 1000000);

    hipLaunchKernelGGL(kA, dim3(4), dim3(512), 0, stream,
                       ei, Wl, bl, Wr, br, att, P, lin3g, offsG, slots);
    // --- diagnostics (scratch / overwritten output) ---
    hipLaunchKernelGGL(kD2, dim3(4, G_), dim3(512), 0, stream,
                       x, P, lin3g, offsG, slots, scr);
    hipLaunchKernelGGL(kD3, dim3(4, G_), dim3(512), 0, stream,
                       x, P, lin3g, offsG, slots, scr);
    hipLaunchKernelGGL(kD4, dim3(4, G_), dim3(512), 0, stream,
                       Wl, bl, bias, out);
    // --- real pipeline ---
    hipLaunchKernelGGL(kF, dim3(4, G_), dim3(512), 0, stream,
                       x, P, lin3g, offsG, slots, Wl, bl, bias, out);
}

// Round 12
// 55.238 us; speedup vs baseline: 13.3734x; 13.3734x over previous
//
#include <hip/hip_runtime.h>
#include <math.h>

#define G_ 320
#define N_ 1000
#define T_ 10
#define C_ 96
#define E_ 8000
#define QN 250          // nodes per quarter (4 quarters)
#define CAP 2816        // slot capacity per quarter (mean ~2250, >14 sigma)
#define EPT 5           // slots per thread in main logit pass
#define NT 1025         // table entries per half (t in [-1,1], 1024 intervals)

// ws layout (bytes):
//       0: P      96 float4      (wl, wr, bl+br, 0.4*att)   [fallback path]
//    1536: lin4   4 f            (0.6A, 0.6B, 0.6Cb, homog_flag)
//    1552: offsG  4*251 i        (per-quarter LOCAL CSR offsets)
//    5568: slots  4*CAP int2     (per-quarter packed (src,dst))
//   95680: tabG   2*NT f         (h1 | h2 tables, 0.4*att folded in)

// ---------------- kA: CSR build + tables, one block per quarter ----------------
__global__ __launch_bounds__(512) void kA(
        const int* __restrict__ ei,
        const float* __restrict__ Wl, const float* __restrict__ bl,
        const float* __restrict__ Wr, const float* __restrict__ br,
        const float* __restrict__ att,
        float4* __restrict__ P, float* __restrict__ lin4,
        int* __restrict__ offsG, int2* __restrict__ slots,
        float* __restrict__ tabG) {
    __shared__ int cnt[256], cur[256], offsL[260];
    const int tid = threadIdx.x;
    const int q = blockIdx.x;
    const int lo = q * QN;

    if (q == 0) {   // params + lin + homogeneity flag + 1D tables
        if (tid < C_)
            P[tid] = make_float4(Wl[tid], Wr[tid], bl[tid] + br[tid], 0.4f * att[tid]);
        int w = tid >> 6, lane = tid & 63;
        if (w < 3) {
            float s = 0.f;
            for (int i = lane; i < C_; i += 64) {
                float a = att[i];
                float m = (w == 0) ? Wl[i] : (w == 1) ? Wr[i] : (bl[i] + br[i]);
                s += a * m;
            }
            for (int off = 32; off; off >>= 1) s += __shfl_down(s, off);
            if (lane == 0) lin4[w] = 0.6f * s;
        }
        if (tid == 0) {
            float m = 0.f;
            for (int c = 0; c < C_; c++) m = fmaxf(m, fabsf(bl[c] + br[c]));
            lin4[3] = (m == 0.f) ? 1.f : 0.f;   // homogeneous => table path valid
        }
        // tables: tab[0][j] = sum 0.4*a_c*|wl_c + t_j*wr_c| ; tab[1][j] with roles swapped
        for (int i = tid; i < 2 * NT; i += 512) {
            int which = i / NT;
            int j = i - which * NT;
            float t = -1.f + (float)j * (2.f / 1024.f);
            float s = 0.f;
            for (int c = 0; c < C_; c++) {
                float wl = Wl[c], wr = Wr[c];
                float val = which ? fmaf(t, wl, wr) : fmaf(t, wr, wl);
                s = fmaf(0.4f * att[c], fabsf(val), s);
            }
            tabG[i] = s;
        }
    }
    for (int i = tid; i < 256; i += 512) cnt[i] = (i < QN) ? 1 : 0; // self-loop
    __syncthreads();

    const int4* d4 = (const int4*)(ei + E_);
    const int4* s4 = (const int4*)ei;
    for (int j = tid; j < E_ / 4; j += 512) {
        int4 d = d4[j];
        int r0 = d.x - lo, r1 = d.y - lo, r2 = d.z - lo, r3 = d.w - lo;
        if ((unsigned)r0 < (unsigned)QN) atomicAdd(&cnt[r0], 1);
        if ((unsigned)r1 < (unsigned)QN) atomicAdd(&cnt[r1], 1);
        if ((unsigned)r2 < (unsigned)QN) atomicAdd(&cnt[r2], 1);
        if ((unsigned)r3 < (unsigned)QN) atomicAdd(&cnt[r3], 1);
    }
    __syncthreads();

    if (tid < 64) {   // wave-0 shuffle scan, lane owns 4 counters
        int b4 = tid * 4;
        int a0 = cnt[b4], a1 = cnt[b4 + 1], a2 = cnt[b4 + 2], a3 = cnt[b4 + 3];
        int s1 = a0 + a1, s2 = s1 + a2, s3 = s2 + a3;
        int pre = s3;
        for (int off = 1; off < 64; off <<= 1) {
            int tv = __shfl_up(pre, off);
            if (tid >= off) pre += tv;
        }
        int base = pre - s3;
        offsL[b4] = base;          cur[b4] = base;
        offsL[b4 + 1] = base + a0; cur[b4 + 1] = base + a0;
        offsL[b4 + 2] = base + s1; cur[b4 + 2] = base + s1;
        offsL[b4 + 3] = base + s2; cur[b4 + 3] = base + s2;
    }
    __syncthreads();

    int2* sl = slots + (size_t)q * CAP;
    for (int j = tid; j < E_ / 4; j += 512) {
        int4 d = d4[j];
        int4 s = s4[j];
#define SCAT(DD, SS) { int r = (DD) - lo;                                    \
        if ((unsigned)r < (unsigned)QN) {                                    \
            int pos = atomicAdd(&cur[r], 1);                                 \
            sl[pos] = make_int2((SS), (DD)); } }
        SCAT(d.x, s.x) SCAT(d.y, s.y) SCAT(d.z, s.z) SCAT(d.w, s.w)
#undef SCAT
    }
    for (int i = tid; i < QN; i += 512) {       // self-loops
        int pos = atomicAdd(&cur[i], 1);
        sl[pos] = make_int2(lo + i, lo + i);
    }
    for (int i = tid; i <= QN; i += 512) offsG[q * (QN + 1) + i] = offsL[i];
}

// ------- kF: table-logits + softmax + expansion, per (quarter, graph) -------
__global__ __launch_bounds__(512, 4) void kF(
        const float* __restrict__ x, const float4* __restrict__ P,
        const float* __restrict__ lin4, const int* __restrict__ offsG,
        const int2* __restrict__ slots, const float* __restrict__ tabG,
        const float* __restrict__ Wl, const float* __restrict__ bl,
        const float* __restrict__ bias, float4* __restrict__ out) {
    __shared__ float xgs[N_];
    __shared__ float L[CAP];
    __shared__ float U[CAP];
    __shared__ float tabL[2 * NT];
    __shared__ int offsL[QN + 1];
    __shared__ float Sloc[QN];
    __shared__ float4 wl4[C_ / 4], cb4[C_ / 4];
    const int tid = threadIdx.x;
    const int q = blockIdx.x;
    const int g = blockIdx.y;
    const int lo = q * QN;
    const int t = g % T_;

    const float* xg = x + g * N_;
    if (tid < N_ / 4) ((float4*)xgs)[tid] = ((const float4*)xg)[tid];
    for (int i = tid; i < 2 * NT; i += 512) tabL[i] = tabG[i];
    for (int i = tid; i <= QN; i += 512) offsL[i] = offsG[q * (QN + 1) + i];
    if (tid < C_) {   // expansion tables (wl, combined bias+pos)
        int k2 = tid & ~1;
        float dt = __expf(-(float)k2 * (logf(10000.0f) / (float)C_));
        float ang = (float)t * dt;
        float pe = (tid & 1) ? cosf(ang) : sinf(ang);
        ((float*)wl4)[tid] = Wl[tid];
        ((float*)cb4)[tid] = bl[tid] + bias[tid] + pe;
    }
    __syncthreads();
    const int cntE = offsL[QN];
    const float la = lin4[0], lb = lin4[1], lc = lin4[2];
    const bool homog = (lin4[3] != 0.f);        // uniform branch
    const int2* sl = slots + (size_t)q * CAP;

    if (homog) {
        // fast path: e = lin + big * lerp(tab, t), t = small/big ratio
        float u[EPT], v[EPT];
#pragma unroll
        for (int k = 0; k < EPT; k++) {
            int p = tid + k * 512;
            int2 sd = sl[p < cntE ? p : 0];
            u[k] = xgs[sd.x]; v[k] = xgs[sd.y];
        }
#pragma unroll
        for (int k = 0; k < EPT; k++) {
            int p = tid + k * 512;
            if (p >= cntE) continue;
            float uu = u[k], vv = v[k];
            float au = fabsf(uu), av = fabsf(vv);
            bool ub = au >= av;
            float big = ub ? au : av;
            float den = ub ? uu : vv;
            float oth = ub ? vv : uu;
            float tt = oth / den;                       // exact div; NaN if 0/0
            tt = fmaxf(fminf(tt, 1.f), -1.f);           // sanitizes NaN too
            float fi = fmaf(tt, 512.f, 512.f);          // [0,1024]
            int i0 = (int)fi; i0 = min(i0, 1023);
            float fr = fi - (float)i0;
            int bse = ub ? 0 : NT;
            float t0 = tabL[bse + i0], t1 = tabL[bse + i0 + 1];
            float e = fmaf(big, fmaf(fr, t1 - t0, t0),
                           fmaf(uu, la, fmaf(vv, lb, lc)));
            L[p] = e; U[p] = uu;
        }
        for (int p = tid + 512 * EPT; p < cntE; p += 512) {   // rare overflow
            int2 sd = sl[p];
            float uu = xgs[sd.x], vv = xgs[sd.y];
            float au = fabsf(uu), av = fabsf(vv);
            bool ub = au >= av;
            float big = ub ? au : av;
            float tt = (ub ? vv : uu) / (ub ? uu : vv);
            tt = fmaxf(fminf(tt, 1.f), -1.f);
            float fi = fmaf(tt, 512.f, 512.f);
            int i0 = (int)fi; i0 = min(i0, 1023);
            float fr = fi - (float)i0;
            int bse = ub ? 0 : NT;
            float t0 = tabL[bse + i0], t1 = tabL[bse + i0 + 1];
            L[p] = fmaf(big, fmaf(fr, t1 - t0, t0),
                        fmaf(uu, la, fmaf(vv, lb, lc)));
            U[p] = uu;
        }
    } else {
        // exact fallback (bb != 0): simple low-register per-slot loop
        for (int p = tid; p < cntE; p += 512) {
            int2 sd = sl[p];
            float uu = xgs[sd.x], vv = xgs[sd.y], a2 = 0.f;
            for (int c = 0; c < C_; c++) {
                float4 qv = P[c];
                float wv = fmaf(uu, qv.x, fmaf(vv, qv.y, qv.z));
                a2 = fmaf(qv.w, fabsf(wv), a2);
            }
            L[p] = fmaf(uu, la, fmaf(vv, lb, lc)) + a2;
            U[p] = uu;
        }
    }
    __syncthreads();

    // per-node branchless online softmax -> Sloc
    if (tid < QN) {
        int a = offsL[tid], b = offsL[tid + 1];
        float m = -INFINITY, den = 0.f, num = 0.f;
        for (int p = a; p < b; ++p) {
            float l = L[p], uu = U[p];
            float nm = fmaxf(m, l);
            float sc = __expf(m - nm);
            float ex = __expf(l - nm);
            den = den * sc + ex;
            num = fmaf(ex, uu, num * sc);
            m = nm;
        }
        Sloc[tid] = num / den;
    }
    __syncthreads();

    // expansion: contiguous 250x24-float4 slab; incremental i/24 (512=21*24+8)
    float4* out4 = out + (size_t)(g * N_ + lo) * (C_ / 4);
    int node = tid / 24, c4 = tid % 24;
    for (int i = tid; i < QN * (C_ / 4); i += 512) {
        float s = Sloc[node];
        float4 wv = wl4[c4], cb = cb4[c4];
        out4[i] = make_float4(fmaf(s, wv.x, cb.x), fmaf(s, wv.y, cb.y),
                              fmaf(s, wv.z, cb.z), fmaf(s, wv.w, cb.w));
        int c4n = c4 + 8;
        int carry = (c4n >= 24) ? 1 : 0;
        node += 21 + carry;
        c4 = c4n - (carry ? 24 : 0);
    }
}

extern "C" void kernel_launch(void* const* d_in, const int* in_sizes, int n_in,
                              void* d_out, int out_size, void* d_ws, size_t ws_size,
                              hipStream_t stream) {
    const float* x    = (const float*)d_in[0];
    const int*   ei   = (const int*)d_in[1];
    const float* Wl   = (const float*)d_in[2];
    const float* bl   = (const float*)d_in[3];
    const float* Wr   = (const float*)d_in[4];
    const float* br   = (const float*)d_in[5];
    const float* att  = (const float*)d_in[6];
    const float* bias = (const float*)d_in[7];
    float4* out = (float4*)d_out;

    char* ws = (char*)d_ws;
    float4* P     = (float4*)(ws + 0);
    float*  lin4  = (float*)(ws + 1536);
    int*    offsG = (int*)(ws + 1552);
    int2*   slots = (int2*)(ws + 5568);
    float*  tabG  = (float*)(ws + 95680);

    hipLaunchKernelGGL(kA, dim3(4), dim3(512), 0, stream,
                       ei, Wl, bl, Wr, br, att, P, lin4, offsG, slots, tabG);
    hipLaunchKernelGGL(kF, dim3(4, G_), dim3(512), 0, stream,
                       x, P, lin4, offsG, slots, tabG, Wl, bl, bias, out);
}